// Round 5
// baseline (319.203 us; speedup 1.0000x reference)
//
#include <hip/hip_runtime.h>
#include <math.h>

#define S 2048
#define B 16
#define H 512
#define L 4096
#define SMAX 16
#define LAB 256
#define V 32000
#define NCH 250          // V / 128 vocab chunks
#define LOG2E 1.44269504f

typedef __attribute__((ext_vector_type(8))) short short8;
typedef __attribute__((ext_vector_type(4))) float float4v;

__device__ inline ushort f2bf(float x) {
  union { float f; unsigned u; } c; c.f = x;
  unsigned r = c.u + 0x7fffu + ((c.u >> 16) & 1u);
  return (ushort)(r >> 16);
}
__device__ inline float bf2f(ushort h) {
  union { unsigned u; float f; } c; c.u = ((unsigned)h) << 16;
  return c.f;
}

// ---------------------------------------------------------------- kernel A
// span gather -> spanb bf16 [L][1536] = concat(left, mean, right)
__global__ __launch_bounds__(256) void spanb_kernel(
    const float* __restrict__ hidden, const int* __restrict__ begins,
    const int* __restrict__ ends, const int* __restrict__ bids,
    ushort* __restrict__ spanb) {
  int sub = threadIdx.x >> 7, t = threadIdx.x & 127;
  int l = blockIdx.x * 2 + sub;
  int b = bids[l], s0 = begins[l], s1 = ends[l];
  const float4* hidv = (const float4*)hidden;
  float4 lf = hidv[((size_t)(s0 - 1) * B + b) * 128 + t];
  float4 rf = hidv[((size_t)s1 * B + b) * 128 + t];
  float4 m = make_float4(0.f, 0.f, 0.f, 0.f);
  int len = s1 - s0;
  for (int j = 0; j < len; ++j) {
    float4 g = hidv[((size_t)(s0 + j) * B + b) * 128 + t];
    m.x += g.x; m.y += g.y; m.z += g.z; m.w += g.w;
  }
  float inv = 1.0f / (float)len;
  ushort* sp = spanb + (size_t)l * 1536;
  ushort4 u;
  u.x = f2bf(lf.x); u.y = f2bf(lf.y); u.z = f2bf(lf.z); u.w = f2bf(lf.w);
  *(ushort4*)&sp[t * 4] = u;
  u.x = f2bf(m.x * inv); u.y = f2bf(m.y * inv);
  u.z = f2bf(m.z * inv); u.w = f2bf(m.w * inv);
  *(ushort4*)&sp[512 + t * 4] = u;
  u.x = f2bf(rf.x); u.y = f2bf(rf.y); u.z = f2bf(rf.z); u.w = f2bf(rf.w);
  *(ushort4*)&sp[1024 + t * 4] = u;
}

// ---------------------------------------------------------------- kernel B
// generic transpose+cast: src[K][N] f32 -> dst[N][K] bf16
__global__ __launch_bounds__(256) void tcast_kernel(
    const float* __restrict__ src, ushort* __restrict__ dst, int K, int N) {
  __shared__ ushort tile[64 * 72];
  int t = threadIdx.x;
  int n0 = blockIdx.x * 64;
  int k0 = blockIdx.y * 64;
  #pragma unroll
  for (int p = 0; p < 16; ++p) {
    int k = p * 4 + (t >> 6);
    int n = t & 63;
    tile[n * 72 + k] = f2bf(src[(size_t)(k0 + k) * N + n0 + n]);
  }
  __syncthreads();
  #pragma unroll
  for (int p = 0; p < 2; ++p) {
    int idx = p * 256 + t;
    int n = idx >> 3, c = idx & 7;
    *(uint4*)&dst[(size_t)(n0 + n) * K + k0 + c * 8] =
        *(const uint4*)&tile[n * 72 + c * 8];
  }
}

// ---------------------------------------------------------------- kernel C
// MFMA MLP: featb = bf16( sigmoid(spanb@W1+b1) @ W2 + b2 )
#define FST 72
__global__ __launch_bounds__(256, 2) void feat_mfma_kernel(
    const ushort* __restrict__ spanb, const ushort* __restrict__ W1b,
    const float* __restrict__ b1, const ushort* __restrict__ W2b,
    const float* __restrict__ b2, ushort* __restrict__ featb) {
  __shared__ ushort As[32 * FST];
  __shared__ ushort Bs[256 * FST];
  __shared__ ushort Hs[32 * 264];
  int tid = threadIdx.x;
  int w = tid >> 6, lane = tid & 63;
  int lr = lane & 15, lq = lane >> 4;
  int l0 = blockIdx.x * 32;

  float4v acc[2][4];
  float4v zero = {0.f, 0.f, 0.f, 0.f};
  #pragma unroll
  for (int mt = 0; mt < 2; ++mt)
    #pragma unroll
    for (int nt = 0; nt < 4; ++nt) acc[mt][nt] = zero;

  for (int s = 0; s < 24; ++s) {
    int ks = s * 64;
    __syncthreads();
    {
      int r = tid >> 3, c = tid & 7;
      *(uint4*)&As[r * FST + c * 8] =
          *(const uint4*)&spanb[(size_t)(l0 + r) * 1536 + ks + c * 8];
    }
    #pragma unroll
    for (int p = 0; p < 8; ++p) {
      int idx = p * 256 + tid;
      int r = idx >> 3, c = idx & 7;
      *(uint4*)&Bs[r * FST + c * 8] =
          *(const uint4*)&W1b[(size_t)r * 1536 + ks + c * 8];
    }
    __syncthreads();
    #pragma unroll
    for (int kk = 0; kk < 2; ++kk) {
      short8 af[2], bf[4];
      #pragma unroll
      for (int mt = 0; mt < 2; ++mt)
        af[mt] = *(const short8*)&As[(mt * 16 + lr) * FST + kk * 32 + lq * 8];
      #pragma unroll
      for (int nt = 0; nt < 4; ++nt)
        bf[nt] = *(const short8*)
            &Bs[(w * 64 + nt * 16 + lr) * FST + kk * 32 + lq * 8];
      #pragma unroll
      for (int mt = 0; mt < 2; ++mt)
        #pragma unroll
        for (int nt = 0; nt < 4; ++nt)
          acc[mt][nt] = __builtin_amdgcn_mfma_f32_16x16x32_bf16(
              af[mt], bf[nt], acc[mt][nt], 0, 0, 0);
    }
  }

  {
    float b1v[4];
    #pragma unroll
    for (int nt = 0; nt < 4; ++nt) b1v[nt] = b1[w * 64 + nt * 16 + lr];
    #pragma unroll
    for (int mt = 0; mt < 2; ++mt)
      #pragma unroll
      for (int nt = 0; nt < 4; ++nt)
        #pragma unroll
        for (int r = 0; r < 4; ++r) {
          int row = mt * 16 + lq * 4 + r;
          int col = w * 64 + nt * 16 + lr;
          float h = 1.0f / (1.0f + __expf(-(acc[mt][nt][r] + b1v[nt])));
          Hs[row * 264 + col] = f2bf(h);
        }
  }

  float4v acc2[2][4];
  #pragma unroll
  for (int mt = 0; mt < 2; ++mt)
    #pragma unroll
    for (int nt = 0; nt < 4; ++nt) acc2[mt][nt] = zero;

  for (int s = 0; s < 4; ++s) {
    int ks = s * 64;
    __syncthreads();
    #pragma unroll
    for (int p = 0; p < 8; ++p) {
      int idx = p * 256 + tid;
      int r = idx >> 3, c = idx & 7;
      *(uint4*)&Bs[r * FST + c * 8] =
          *(const uint4*)&W2b[(size_t)r * 256 + ks + c * 8];
    }
    __syncthreads();
    #pragma unroll
    for (int kk = 0; kk < 2; ++kk) {
      short8 af[2], bf[4];
      #pragma unroll
      for (int mt = 0; mt < 2; ++mt)
        af[mt] = *(const short8*)
            &Hs[(mt * 16 + lr) * 264 + ks + kk * 32 + lq * 8];
      #pragma unroll
      for (int nt = 0; nt < 4; ++nt)
        bf[nt] = *(const short8*)
            &Bs[(w * 64 + nt * 16 + lr) * FST + kk * 32 + lq * 8];
      #pragma unroll
      for (int mt = 0; mt < 2; ++mt)
        #pragma unroll
        for (int nt = 0; nt < 4; ++nt)
          acc2[mt][nt] = __builtin_amdgcn_mfma_f32_16x16x32_bf16(
              af[mt], bf[nt], acc2[mt][nt], 0, 0, 0);
    }
  }

  {
    float b2v[4];
    #pragma unroll
    for (int nt = 0; nt < 4; ++nt) b2v[nt] = b2[w * 64 + nt * 16 + lr];
    #pragma unroll
    for (int mt = 0; mt < 2; ++mt)
      #pragma unroll
      for (int nt = 0; nt < 4; ++nt)
        #pragma unroll
        for (int r = 0; r < 4; ++r) {
          int row = mt * 16 + lq * 4 + r;
          int col = w * 64 + nt * 16 + lr;
          featb[(size_t)(l0 + row) * 256 + col] =
              f2bf(acc2[mt][nt][r] + b2v[nt]);
        }
  }
}

// ---------------------------------------------------------------- kernel D
// Logits + sumexp partials. Chunk-major grid: blockIdx.x = vocab chunk
// (consecutive blocks share the label-block -> featb slice stays L2-hot;
// a chunk's 16 blocks span only 4 XCDs since 250 % 8 == 2).
// 4 waves; wave w: rows l0+w*64..+63 (4 mt), all 128 cols (8 nt).
// A-frags load-use from global (no double-buffer -> no spills);
// B chunk staged once to LDS.
#define BST2 264
__global__ __launch_bounds__(256, 2) void logits3_kernel(
    const ushort* __restrict__ featb, const ushort* __restrict__ Wob,
    const float* __restrict__ bo, float* __restrict__ pz) {
  __shared__ ushort Blds[128 * BST2];    // 66 KB
  int tid = threadIdx.x;
  int ch = blockIdx.x;                   // 0..249
  int l0 = blockIdx.y * 256;             // 0..15 label blocks
  int v0 = ch * 128;
  int w = tid >> 6, lane = tid & 63;
  int lr = lane & 15, lq = lane >> 4;

  // stage B: 128 rows x 256 ushorts = 4096 uint4, coalesced
  {
    const uint4* src = (const uint4*)(Wob + (size_t)v0 * 256);
    #pragma unroll
    for (int p = 0; p < 16; ++p) {
      int idx = p * 256 + tid;
      int r = idx >> 5, c = idx & 31;
      *(uint4*)&Blds[r * BST2 + c * 8] = src[idx];
    }
  }
  __syncthreads();                       // the only barrier

  float4v acc[4][8];
  float4v zero = {0.f, 0.f, 0.f, 0.f};
  #pragma unroll
  for (int mt = 0; mt < 4; ++mt)
    #pragma unroll
    for (int nt = 0; nt < 8; ++nt) acc[mt][nt] = zero;

  // lane's A base: row (l0 + w*64 + lr), 16B sub-chunk lq
  const ushort* abase = featb + (size_t)(l0 + w * 64 + lr) * 256 + lq * 8;

  #pragma unroll
  for (int k = 0; k < 8; ++k) {          // K = 8 steps of 32
    short8 af[4];
    #pragma unroll
    for (int mt = 0; mt < 4; ++mt)
      af[mt] = *(const short8*)(abase + mt * 16 * 256 + k * 32);
    short8 bf[8];
    #pragma unroll
    for (int nt = 0; nt < 8; ++nt)
      bf[nt] = *(const short8*)&Blds[(nt * 16 + lr) * BST2 + k * 32 + lq * 8];
    #pragma unroll
    for (int mt = 0; mt < 4; ++mt)
      #pragma unroll
      for (int nt = 0; nt < 8; ++nt)
        acc[mt][nt] = __builtin_amdgcn_mfma_f32_16x16x32_bf16(
            af[mt], bf[nt], acc[mt][nt], 0, 0, 0);
  }

  // epilogue: z[row] = sum_cols exp(logit + bo), no max (logits bounded)
  float bov[8];
  #pragma unroll
  for (int nt = 0; nt < 8; ++nt)
    bov[nt] = bo[v0 + nt * 16 + lr] * LOG2E;
  float z[4][4];
  #pragma unroll
  for (int mt = 0; mt < 4; ++mt)
    #pragma unroll
    for (int r = 0; r < 4; ++r) z[mt][r] = 0.f;
  #pragma unroll
  for (int mt = 0; mt < 4; ++mt)
    #pragma unroll
    for (int nt = 0; nt < 8; ++nt)
      #pragma unroll
      for (int r = 0; r < 4; ++r)
        z[mt][r] += exp2f(fmaf(acc[mt][nt][r], LOG2E, bov[nt]));
  #pragma unroll
  for (int mt = 0; mt < 4; ++mt)
    #pragma unroll
    for (int r = 0; r < 4; ++r) {
      #pragma unroll
      for (int off = 1; off < 16; off <<= 1)
        z[mt][r] += __shfl_xor(z[mt][r], off);
    }
  if (lr == 0) {
    #pragma unroll
    for (int mt = 0; mt < 4; ++mt)
      #pragma unroll
      for (int r = 0; r < 4; ++r)
        pz[(size_t)ch * L + l0 + w * 64 + mt * 16 + lq * 4 + r] = z[mt][r];
  }
}

// ---------------------------------------------------------------- kernel E
// Exact tag logit: tagl[l] = featb[l]·Wob[tags[l]] + bo[tags[l]]
__global__ __launch_bounds__(256) void tag_kernel(
    const ushort* __restrict__ featb, const ushort* __restrict__ Wob,
    const float* __restrict__ bo, const int* __restrict__ tags,
    float* __restrict__ tagl) {
  int l = blockIdx.x * 4 + (threadIdx.x >> 6);
  int lane = threadIdx.x & 63;
  int tg = tags[l];
  ushort4 fa = *(const ushort4*)&featb[(size_t)l * 256 + lane * 4];
  ushort4 wa = *(const ushort4*)&Wob[(size_t)tg * 256 + lane * 4];
  float s = bf2f(fa.x) * bf2f(wa.x) + bf2f(fa.y) * bf2f(wa.y) +
            bf2f(fa.z) * bf2f(wa.z) + bf2f(fa.w) * bf2f(wa.w);
  #pragma unroll
  for (int off = 1; off < 64; off <<= 1) s += __shfl_xor(s, off);
  if (lane == 0) tagl[l] = s + bo[tg];
}

// ---------------------------------------------------------------- kernel F
__global__ __launch_bounds__(256) void reduce_kernel(
    const float* __restrict__ pz, const float* __restrict__ tagl,
    float* __restrict__ out) {
  int l = blockIdx.x * 256 + threadIdx.x;
  float z = 0.f;
  for (int c = 0; c < NCH; ++c) z += pz[(size_t)c * L + l];
  float per = logf(z) - tagl[l];
  float v = per * (1.0f / (4096.0f + 1e-5f));
  #pragma unroll
  for (int off = 1; off < 64; off <<= 1) v += __shfl_xor(v, off);
  __shared__ float wsum[4];
  if ((threadIdx.x & 63) == 0) wsum[threadIdx.x >> 6] = v;
  __syncthreads();
  if (threadIdx.x == 0)
    atomicAdd(out, wsum[0] + wsum[1] + wsum[2] + wsum[3]);
}

// ---------------------------------------------------------------- launch
extern "C" void kernel_launch(void* const* d_in, const int* in_sizes, int n_in,
                              void* d_out, int out_size, void* d_ws,
                              size_t ws_size, hipStream_t stream) {
  const float* hidden = (const float*)d_in[0];
  const int* begins = (const int*)d_in[1];
  const int* ends = (const int*)d_in[2];
  const int* bids = (const int*)d_in[3];
  const int* tags = (const int*)d_in[4];
  const float* W1 = (const float*)d_in[5];
  const float* b1 = (const float*)d_in[6];
  const float* W2 = (const float*)d_in[7];
  const float* b2 = (const float*)d_in[8];
  const float* Wo = (const float*)d_in[9];
  const float* bo = (const float*)d_in[10];
  float* out = (float*)d_out;

  ushort* featb = (ushort*)d_ws;                       // L*256
  ushort* Wob = featb + (size_t)L * 256;               // V*256
  ushort* spanb = Wob + (size_t)V * 256;               // L*1536
  ushort* W1b = spanb + (size_t)L * 1536;              // 256*1536
  ushort* W2b = W1b + (size_t)256 * 1536;              // 256*256
  float* pz = (float*)(W2b + (size_t)256 * 256);       // NCH*L
  float* tagl = pz + (size_t)NCH * L;                  // L

  hipMemsetAsync(d_out, 0, sizeof(float), stream);
  spanb_kernel<<<L / 2, 256, 0, stream>>>(hidden, begins, ends, bids, spanb);
  tcast_kernel<<<dim3(4, 24), 256, 0, stream>>>(W1, W1b, 1536, LAB);
  tcast_kernel<<<dim3(4, 4), 256, 0, stream>>>(W2, W2b, LAB, LAB);
  tcast_kernel<<<dim3(500, 4), 256, 0, stream>>>(Wo, Wob, LAB, V);
  feat_mfma_kernel<<<128, 256, 0, stream>>>(spanb, W1b, b1, W2b, b2, featb);
  logits3_kernel<<<dim3(NCH, 16), 256, 0, stream>>>(featb, Wob, bo, pz);
  tag_kernel<<<L / 4, 256, 0, stream>>>(featb, Wob, bo, tags, tagl);
  reduce_kernel<<<L / 256, 256, 0, stream>>>(pz, tagl, out);
}